// Round 14
// baseline (2987.903 us; speedup 1.0000x reference)
//
#include <hip/hip_runtime.h>

typedef unsigned int uint;
typedef unsigned short ushort;
typedef unsigned long long u64;
typedef short bf16x8 __attribute__((ext_vector_type(8)));
typedef float f32x4 __attribute__((ext_vector_type(4)));

// ---------------- workspace layout (bytes) ----------------
// xw2: ushort [2 dir][16 bgrp][1024 t][4 b][1024 col'] = 256MB, col' = u*4+g
#define XW_OFF   0ull
#define XB_OFF   (XW_OFF + 268435456ull)     // ushort [64*1024*256] x in bf16
#define WT_OFF   (XB_OFF + 33554432ull)      // ushort [2][1024 col'][256]  W^T bf16 (permuted cols)
#define UT_OFF   (WT_OFF + 1048576ull)       // ushort [2][1024 col'][256]  U^T bf16 (permuted cols)
#define WS_NEED  (UT_OFF + 1048576ull)

static __device__ __forceinline__ ushort f2bf(float f) {
  uint u = __float_as_uint(f);
  return (ushort)((u + 0x7fffu + ((u >> 16) & 1u)) >> 16);
}
static __device__ __forceinline__ float bf2f(ushort s) {
  return __uint_as_float((uint)s << 16);
}
static __device__ __forceinline__ float fsig(float x) {
  return 1.0f / (1.0f + __expf(-x));
}
static __device__ __forceinline__ float ftanh(float x) {
  return 1.0f - 2.0f / (__expf(2.0f * x) + 1.0f);
}

// global->LDS direct copy, 16B per lane (dest = wave-uniform base + lane*16)
static __device__ __forceinline__ void gload_lds16(const void* g, void* l) {
  auto gp = (const __attribute__((address_space(1))) uint*)((const void*)g);
  auto lp = (__attribute__((address_space(3))) uint*)((void*)l);
  __builtin_amdgcn_global_load_lds(gp, lp, 16, 0, 0);
}

// ================= convert: x->bf16, W^T, U^T (gate-interleaved cols) =========
// col' = u*4 + g  ->  orig col = (col'&3)*256 + (col'>>2)
__global__ __launch_bounds__(256) void k_convert(
    const float* __restrict__ x,
    const float* __restrict__ Wf, const float* __restrict__ Wb,
    const float* __restrict__ Uf, const float* __restrict__ Ub,
    ushort* __restrict__ xb, ushort* __restrict__ wt, ushort* __restrict__ ut)
{
  uint tid = blockIdx.x * 256u + threadIdx.x;
  if (tid < 2097152u) {
    uint base = tid * 8u;
    float4 a = *(const float4*)(x + base);
    float4 b = *(const float4*)(x + base + 4);
    uint4 o;
    o.x = (uint)f2bf(a.x) | ((uint)f2bf(a.y) << 16);
    o.y = (uint)f2bf(a.z) | ((uint)f2bf(a.w) << 16);
    o.z = (uint)f2bf(b.x) | ((uint)f2bf(b.y) << 16);
    o.w = (uint)f2bf(b.z) | ((uint)f2bf(b.w) << 16);
    *(uint4*)(xb + base) = o;
  } else {
    uint e = tid - 2097152u;
    uint which = e >> 18;
    uint i = e & 262143u;
    uint n = i >> 8, k = i & 255u;          // n = permuted col'
    uint orig = (n & 3u) * 256u + (n >> 2); // original gate-major col
    const float* src = (which == 0) ? Wf : (which == 1) ? Wb : (which == 2) ? Uf : Ub;
    ushort v = f2bf(src[k * 1024u + orig]);
    ushort* dst = (which < 2) ? (wt + which * 262144u) : (ut + (which - 2u) * 262144u);
    dst[n * 256u + k] = v;
  }
}

// ================= GEMM: xw2[dir][bgrp][t][b][col'] = x @ W + bias ======
__global__ __launch_bounds__(256) void k_gemm(
    const ushort* __restrict__ xb, const ushort* __restrict__ wt,
    const float* __restrict__ biasF, const float* __restrict__ biasB,
    ushort* __restrict__ xw2)
{
  const int dir = blockIdx.z;
  const ushort* W = wt + dir * 262144;
  const float* bias = dir ? biasB : biasF;
  const int m0 = blockIdx.x * 128;   // (b, t) rows
  const int n0 = blockIdx.y * 128;   // permuted gate-col block
  const int tid = threadIdx.x;
  const int lane = tid & 63, wave = tid >> 6;
  const int l15 = lane & 15, l4 = lane >> 4;
  const int wr = wave >> 1, wc = wave & 1;

  __shared__ __align__(16) ushort lds[17664];
  ushort* As = lds;            // [128][40]
  ushort* Bs = lds + 5120;     // [128][40]

  f32x4 acc[4][4] = {};
  const int arow = tid >> 1, aseg = tid & 1;

  for (int kit = 0; kit < 8; ++kit) {
    int k0 = kit * 32;
    const ushort* sa = xb + (m0 + arow) * 256 + k0 + aseg * 16;
    uint4 a0 = *(const uint4*)sa;
    uint4 a1 = *(const uint4*)(sa + 8);
    const ushort* sb = W + (n0 + arow) * 256 + k0 + aseg * 16;
    uint4 b0 = *(const uint4*)sb;
    uint4 b1 = *(const uint4*)(sb + 8);
    *(uint4*)(As + arow * 40 + aseg * 16) = a0;
    *(uint4*)(As + arow * 40 + aseg * 16 + 8) = a1;
    *(uint4*)(Bs + arow * 40 + aseg * 16) = b0;
    *(uint4*)(Bs + arow * 40 + aseg * 16 + 8) = b1;
    __syncthreads();
    bf16x8 af[4], bfr[4];
#pragma unroll
    for (int m = 0; m < 4; ++m) af[m] = *(const bf16x8*)(As + (wr * 64 + m * 16 + l15) * 40 + l4 * 8);
#pragma unroll
    for (int n = 0; n < 4; ++n) bfr[n] = *(const bf16x8*)(Bs + (wc * 64 + n * 16 + l15) * 40 + l4 * 8);
#pragma unroll
    for (int m = 0; m < 4; ++m)
#pragma unroll
      for (int n = 0; n < 4; ++n)
        acc[m][n] = __builtin_amdgcn_mfma_f32_16x16x32_bf16(af[m], bfr[n], acc[m][n], 0, 0, 0);
    __syncthreads();
  }

  // ---- epilogue: bias (through inverse permutation), bf16, [t_local][col]
  float bv[4];
#pragma unroll
  for (int n = 0; n < 4; ++n) {
    int colp = n0 + wc * 64 + n * 16 + l15;
    bv[n] = bias[(colp & 3) * 256 + (colp >> 2)];
  }
  ushort* tl = lds;   // [128 t][136]
#pragma unroll
  for (int m = 0; m < 4; ++m)
#pragma unroll
    for (int n = 0; n < 4; ++n) {
      int col = wc * 64 + n * 16 + l15;
#pragma unroll
      for (int r = 0; r < 4; ++r) {
        int trow = wr * 64 + m * 16 + l4 * 4 + r;
        tl[trow * 136 + col] = f2bf(acc[m][n][r] + bv[n]);
      }
    }
  __syncthreads();

  // ---- copy out: [t][b][col'], 16B stores
  const int b = m0 >> 10;
  const int bgrp = b >> 2, b_loc = b & 3;
  const int t0 = m0 & 1023;
#pragma unroll
  for (int it = 0; it < 8; ++it) {
    int idx = it * 256 + tid;
    int row = idx >> 4, ch = idx & 15;
    uint4 v = *(const uint4*)(tl + row * 136 + ch * 8);
    u64 off = ((u64)((dir * 16 + bgrp) * 1024 + (t0 + row))) * 4096ull
              + (u64)(b_loc * 1024 + n0 + ch * 8);
    *(uint4*)(xw2 + off) = v;
  }
}

// ================= recurrence: 32 independent blocks, 16 waves each ====
// r13 structure; diff: ALL step inputs preloaded at top of body in latency
// order (xv, uld kt6/7 frags, A frags) so LDS drain overlaps the MFMA phase.
__global__ __launch_bounds__(1024) void k_rec(
    const ushort* __restrict__ xw2, const ushort* __restrict__ ut,
    const float* __restrict__ pif, const float* __restrict__ pff, const float* __restrict__ pof,
    const float* __restrict__ pib, const float* __restrict__ pfb, const float* __restrict__ pob,
    float* __restrict__ out)
{
  const int bid = blockIdx.x;
  const int dir = bid >> 4;
  const int bgrp = bid & 15;
  const int tid = threadIdx.x;
  const int lane = tid & 63, wv = tid >> 6;
  const int l15 = lane & 15, l4 = lane >> 4;
  const int u = wv * 16 + l15;       // unit 0..255

  // LDS: uld 128KB + hst 4.25KB + xsl 24.96KB + trash 1KB
  __shared__ __align__(16) ushort uld[65536];   // [wv][kt-6][g][lane*8]
  __shared__ __align__(16) ushort hst[2176];    // [2 slot][4 b][272]
  __shared__ __align__(16) ushort xsl[12480];   // [3 slot][4 b][1040]
  __shared__ __align__(16) ushort trash[512];

  const float* piP = dir ? pib : pif;
  const float* pfP = dir ? pfb : pff;
  const float* poP = dir ? pob : pof;
  const float ppi = piP[u], ppf = pfP[u], ppo = poP[u];

  // U: kt0..5 in regs (96/lane), kt6..7 in LDS (permuted cols: ut row = u*4+g)
  const ushort* U = ut + dir * 262144;
  bf16x8 ufr[6][4];
#pragma unroll
  for (int g = 0; g < 4; ++g) {
    const ushort* up = U + (u * 4 + g) * 256;
#pragma unroll
    for (int kt = 0; kt < 6; ++kt)
      ufr[kt][g] = *(const bf16x8*)(up + kt * 32 + l4 * 8);
#pragma unroll
    for (int kt = 6; kt < 8; ++kt)
      *(bf16x8*)(uld + wv * 4096 + ((kt - 6) * 4 + g) * 512 + lane * 8) =
          *(const bf16x8*)(up + kt * 32 + l4 * 8);
  }
  for (int i = tid; i < 2176; i += 1024) hst[i] = 0;

  const ushort* xwbase = xw2 + (u64)(dir * 16 + bgrp) * 4194304ull;
  const int sdst = (wv >> 1) * 1040 + (wv & 1) * 512;
  const ushort* ub = uld + wv * 4096 + lane * 8;   // loop-invariant uld base

  // prologue: stage t=0 -> slot0, t=1 -> slot1
  if (tid < 512) {
    const ushort* s0 = xwbase + (u64)(dir ? 1023 : 0) * 4096ull + (uint)tid * 8u;
    const ushort* s1 = xwbase + (u64)(dir ? 1022 : 1) * 4096ull + (uint)tid * 8u;
    gload_lds16(s0, &xsl[sdst]);
    gload_lds16(s1, &xsl[4160 + sdst]);
  }
  asm volatile("s_waitcnt vmcnt(0) lgkmcnt(0)" ::: "memory");
  __syncthreads();

  float cr = 0.f;
  float* outp = out + ((u64)(bgrp * 4 + l4) * 1024ull) * 512ull + (u64)(dir * 256 + u);
  int s_r = 0, s_w = 2;

  for (int t = 0; t < 1024; ++t) {
    // ---- stage for t+2 (issued first; vmcnt deadline is barrier of t+1)
    if (tid < 512) {
      const int tn = (t + 2 < 1024) ? t + 2 : 1023;
      const ushort* src = xwbase + (u64)(dir ? 1023 - tn : tn) * 4096ull + (uint)tid * 8u;
      gload_lds16(src, &xsl[s_w * 4160 + sdst]);
    } else {
      gload_lds16(xwbase + (uint)lane * 8u, trash);
    }

    // ---- preload ALL step inputs (latency-priority order) ----
    // xv first (feeds ew, longest slack ok but tiny), then uld (feeds the
    // LAST MFMAs - hide under kt0-5), then A-frags (feed MFMAs immediately).
    u64 xv = *(const u64*)(xsl + s_r * 4160 + l4 * 1040 + (u << 2));
    bf16x8 u6[4], u7[4];
#pragma unroll
    for (int g = 0; g < 4; ++g) {
      u6[g] = *(const bf16x8*)(ub + g * 512);
      u7[g] = *(const bf16x8*)(ub + 2048 + g * 512);
    }
    const ushort* sA = hst + ((t + 1) & 1) * 1088 + (l15 >> 2) * 272 + l4 * 8;
    bf16x8 a[8];
#pragma unroll
    for (int kt = 0; kt < 8; ++kt)
      a[kt] = *(const bf16x8*)(sA + kt * 32);

    // ---- MFMA: kt0-5 from AGPR ufr, kt6-7 from preloaded u6/u7
    f32x4 acc0 = {0.f, 0.f, 0.f, 0.f}, acc1 = acc0, acc2 = acc0, acc3 = acc0;
#pragma unroll
    for (int kt = 0; kt < 6; ++kt) {
      acc0 = __builtin_amdgcn_mfma_f32_16x16x32_bf16(a[kt], ufr[kt][0], acc0, 0, 0, 0);
      acc1 = __builtin_amdgcn_mfma_f32_16x16x32_bf16(a[kt], ufr[kt][1], acc1, 0, 0, 0);
      acc2 = __builtin_amdgcn_mfma_f32_16x16x32_bf16(a[kt], ufr[kt][2], acc2, 0, 0, 0);
      acc3 = __builtin_amdgcn_mfma_f32_16x16x32_bf16(a[kt], ufr[kt][3], acc3, 0, 0, 0);
    }
    acc0 = __builtin_amdgcn_mfma_f32_16x16x32_bf16(a[6], u6[0], acc0, 0, 0, 0);
    acc1 = __builtin_amdgcn_mfma_f32_16x16x32_bf16(a[6], u6[1], acc1, 0, 0, 0);
    acc2 = __builtin_amdgcn_mfma_f32_16x16x32_bf16(a[6], u6[2], acc2, 0, 0, 0);
    acc3 = __builtin_amdgcn_mfma_f32_16x16x32_bf16(a[6], u6[3], acc3, 0, 0, 0);
    acc0 = __builtin_amdgcn_mfma_f32_16x16x32_bf16(a[7], u7[0], acc0, 0, 0, 0);
    acc1 = __builtin_amdgcn_mfma_f32_16x16x32_bf16(a[7], u7[1], acc1, 0, 0, 0);
    acc2 = __builtin_amdgcn_mfma_f32_16x16x32_bf16(a[7], u7[2], acc2, 0, 0, 0);
    acc3 = __builtin_amdgcn_mfma_f32_16x16x32_bf16(a[7], u7[3], acc3, 0, 0, 0);

    // ---- elementwise: every lane owns (batch=l4, unit=u) via acc[0]
    {
      float cc = cr;
      float gi = acc0[0] + bf2f((ushort)xv);
      float gf = acc1[0] + bf2f((ushort)(xv >> 16));
      float gg = acc2[0] + bf2f((ushort)(xv >> 32));
      float go = acc3[0] + bf2f((ushort)(xv >> 48));
      float iv = fsig(gi + ppi * cc);
      float fv = fsig(gf + ppf * cc);
      float cn = fv * cc + iv * ftanh(gg);
      float ov = fsig(go + ppo * cn);
      float h = ov * ftanh(cn);
      cr = cn;
      hst[(t & 1) * 1088 + l4 * 272 + u] = f2bf(h);
      const int tout = dir ? (1023 - t) : t;
      outp[(u64)tout * 512ull] = h;
    }

    // ---- barrier: keep this step's {gload, store} in flight
    asm volatile("s_waitcnt vmcnt(2) lgkmcnt(0)\n\ts_barrier" ::: "memory");
    s_r = (s_r == 2) ? 0 : s_r + 1;
    s_w = (s_w == 2) ? 0 : s_w + 1;
  }
}

// ================= dropout (exact JAX threefry, in-place on out) =================
#define TFR(r) { x0 += x1; x1 = (x1 << (r)) | (x1 >> (32 - (r))); x1 ^= x0; }
#define RND4A TFR(13) TFR(15) TFR(26) TFR(6)
#define RND4B TFR(17) TFR(29) TFR(16) TFR(24)

static __device__ __forceinline__ void threefry(uint c0, uint c1, uint& y0, uint& y1) {
  const uint k0 = 0u, k1 = 42u;
  const uint ks2 = k0 ^ k1 ^ 0x1BD11BDAu;
  uint x0 = c0 + k0, x1 = c1 + k1;
  RND4A x0 += k1;  x1 += ks2 + 1u;
  RND4B x0 += ks2; x1 += k0 + 2u;
  RND4A x0 += k0;  x1 += k1 + 3u;
  RND4B x0 += k1;  x1 += ks2 + 4u;
  RND4A x0 += ks2; x1 += k0 + 5u;
  y0 = x0; y1 = x1;
}

__global__ __launch_bounds__(256) void k_drop(float* out, uint n) {
  uint i = blockIdx.x * 256u + threadIdx.x;
  if (i < n) {
    uint y0, y1;
    threefry(0u, i, y0, y1);
    uint w = y0 ^ y1;
    float v = out[i];
    out[i] = (w >> 31) ? 0.0f : v * 2.0f;
  }
}

// ================= host =================
extern "C" void kernel_launch(void* const* d_in, const int* in_sizes, int n_in,
                              void* d_out, int out_size, void* d_ws, size_t ws_size,
                              hipStream_t stream)
{
  const float* x   = (const float*)d_in[0];
  const float* Wf  = (const float*)d_in[1];
  const float* Uf  = (const float*)d_in[2];
  const float* bf_ = (const float*)d_in[3];
  const float* pif = (const float*)d_in[4];
  const float* pff = (const float*)d_in[5];
  const float* pof = (const float*)d_in[6];
  const float* Wb  = (const float*)d_in[7];
  const float* Ub  = (const float*)d_in[8];
  const float* bb_ = (const float*)d_in[9];
  const float* pib = (const float*)d_in[10];
  const float* pfb = (const float*)d_in[11];
  const float* pob = (const float*)d_in[12];
  float* out = (float*)d_out;
  char* ws = (char*)d_ws;

  if (ws_size < WS_NEED) {
    hipMemsetAsync(d_out, 0, (size_t)out_size * 4, stream);
    return;
  }

  ushort* xwp = (ushort*)(ws + XW_OFF);
  ushort* xbp = (ushort*)(ws + XB_OFF);
  ushort* wtp = (ushort*)(ws + WT_OFF);
  ushort* utp = (ushort*)(ws + UT_OFF);

  k_convert<<<12288, 256, 0, stream>>>(x, Wf, Wb, Uf, Ub, xbp, wtp, utp);
  k_gemm<<<dim3(512, 8, 2), 256, 0, stream>>>(xbp, wtp, bf_, bb_, xwp);
  k_rec<<<32, 1024, 0, stream>>>(xwp, utp, pif, pff, pof, pib, pfb, pob, out);
  k_drop<<<(out_size + 255) / 256, 256, 0, stream>>>(out, (uint)out_size);
}

// Round 15
// 2237.664 us; speedup vs baseline: 1.3353x; 1.3353x over previous
//
#include <hip/hip_runtime.h>

typedef unsigned int uint;
typedef unsigned short ushort;
typedef unsigned long long u64;
typedef short bf16x8 __attribute__((ext_vector_type(8)));
typedef float f32x4 __attribute__((ext_vector_type(4)));

// ---------------- workspace layout (bytes) ----------------
// xw2: ushort [2 dir][16 bgrp][1024 t][4 b][1024 col'] = 256MB, col' = u*4+g
#define XW_OFF   0ull
#define XB_OFF   (XW_OFF + 268435456ull)     // ushort [64*1024*256] x in bf16
#define WT_OFF   (XB_OFF + 33554432ull)      // ushort [2][1024 col'][256]  W^T bf16 (permuted cols)
#define UT_OFF   (WT_OFF + 1048576ull)       // ushort [2][1024 col'][256]  U^T bf16 (permuted cols)
#define WS_NEED  (UT_OFF + 1048576ull)

static __device__ __forceinline__ ushort f2bf(float f) {
  uint u = __float_as_uint(f);
  return (ushort)((u + 0x7fffu + ((u >> 16) & 1u)) >> 16);
}
static __device__ __forceinline__ float bf2f(ushort s) {
  return __uint_as_float((uint)s << 16);
}
static __device__ __forceinline__ float fsig(float x) {
  return 1.0f / (1.0f + __expf(-x));
}
static __device__ __forceinline__ float ftanh(float x) {
  return 1.0f - 2.0f / (__expf(2.0f * x) + 1.0f);
}

// global->LDS direct copy, 16B per lane (dest = wave-uniform base + lane*16)
static __device__ __forceinline__ void gload_lds16(const void* g, void* l) {
  auto gp = (const __attribute__((address_space(1))) uint*)((const void*)g);
  auto lp = (__attribute__((address_space(3))) uint*)((void*)l);
  __builtin_amdgcn_global_load_lds(gp, lp, 16, 0, 0);
}

// ================= convert: x->bf16, W^T, U^T (gate-interleaved cols) =========
// col' = u*4 + g  ->  orig col = (col'&3)*256 + (col'>>2)
__global__ __launch_bounds__(256) void k_convert(
    const float* __restrict__ x,
    const float* __restrict__ Wf, const float* __restrict__ Wb,
    const float* __restrict__ Uf, const float* __restrict__ Ub,
    ushort* __restrict__ xb, ushort* __restrict__ wt, ushort* __restrict__ ut)
{
  uint tid = blockIdx.x * 256u + threadIdx.x;
  if (tid < 2097152u) {
    uint base = tid * 8u;
    float4 a = *(const float4*)(x + base);
    float4 b = *(const float4*)(x + base + 4);
    uint4 o;
    o.x = (uint)f2bf(a.x) | ((uint)f2bf(a.y) << 16);
    o.y = (uint)f2bf(a.z) | ((uint)f2bf(a.w) << 16);
    o.z = (uint)f2bf(b.x) | ((uint)f2bf(b.y) << 16);
    o.w = (uint)f2bf(b.z) | ((uint)f2bf(b.w) << 16);
    *(uint4*)(xb + base) = o;
  } else {
    uint e = tid - 2097152u;
    uint which = e >> 18;
    uint i = e & 262143u;
    uint n = i >> 8, k = i & 255u;          // n = permuted col'
    uint orig = (n & 3u) * 256u + (n >> 2); // original gate-major col
    const float* src = (which == 0) ? Wf : (which == 1) ? Wb : (which == 2) ? Uf : Ub;
    ushort v = f2bf(src[k * 1024u + orig]);
    ushort* dst = (which < 2) ? (wt + which * 262144u) : (ut + (which - 2u) * 262144u);
    dst[n * 256u + k] = v;
  }
}

// ================= GEMM: xw2[dir][bgrp][t][b][col'] = x @ W + bias ======
__global__ __launch_bounds__(256) void k_gemm(
    const ushort* __restrict__ xb, const ushort* __restrict__ wt,
    const float* __restrict__ biasF, const float* __restrict__ biasB,
    ushort* __restrict__ xw2)
{
  const int dir = blockIdx.z;
  const ushort* W = wt + dir * 262144;
  const float* bias = dir ? biasB : biasF;
  const int m0 = blockIdx.x * 128;   // (b, t) rows
  const int n0 = blockIdx.y * 128;   // permuted gate-col block
  const int tid = threadIdx.x;
  const int lane = tid & 63, wave = tid >> 6;
  const int l15 = lane & 15, l4 = lane >> 4;
  const int wr = wave >> 1, wc = wave & 1;

  __shared__ __align__(16) ushort lds[17664];
  ushort* As = lds;            // [128][40]
  ushort* Bs = lds + 5120;     // [128][40]

  f32x4 acc[4][4] = {};
  const int arow = tid >> 1, aseg = tid & 1;

  for (int kit = 0; kit < 8; ++kit) {
    int k0 = kit * 32;
    const ushort* sa = xb + (m0 + arow) * 256 + k0 + aseg * 16;
    uint4 a0 = *(const uint4*)sa;
    uint4 a1 = *(const uint4*)(sa + 8);
    const ushort* sb = W + (n0 + arow) * 256 + k0 + aseg * 16;
    uint4 b0 = *(const uint4*)sb;
    uint4 b1 = *(const uint4*)(sb + 8);
    *(uint4*)(As + arow * 40 + aseg * 16) = a0;
    *(uint4*)(As + arow * 40 + aseg * 16 + 8) = a1;
    *(uint4*)(Bs + arow * 40 + aseg * 16) = b0;
    *(uint4*)(Bs + arow * 40 + aseg * 16 + 8) = b1;
    __syncthreads();
    bf16x8 af[4], bfr[4];
#pragma unroll
    for (int m = 0; m < 4; ++m) af[m] = *(const bf16x8*)(As + (wr * 64 + m * 16 + l15) * 40 + l4 * 8);
#pragma unroll
    for (int n = 0; n < 4; ++n) bfr[n] = *(const bf16x8*)(Bs + (wc * 64 + n * 16 + l15) * 40 + l4 * 8);
#pragma unroll
    for (int m = 0; m < 4; ++m)
#pragma unroll
      for (int n = 0; n < 4; ++n)
        acc[m][n] = __builtin_amdgcn_mfma_f32_16x16x32_bf16(af[m], bfr[n], acc[m][n], 0, 0, 0);
    __syncthreads();
  }

  // ---- epilogue: bias (through inverse permutation), bf16, [t_local][col]
  float bv[4];
#pragma unroll
  for (int n = 0; n < 4; ++n) {
    int colp = n0 + wc * 64 + n * 16 + l15;
    bv[n] = bias[(colp & 3) * 256 + (colp >> 2)];
  }
  ushort* tl = lds;   // [128 t][136]
#pragma unroll
  for (int m = 0; m < 4; ++m)
#pragma unroll
    for (int n = 0; n < 4; ++n) {
      int col = wc * 64 + n * 16 + l15;
#pragma unroll
      for (int r = 0; r < 4; ++r) {
        int trow = wr * 64 + m * 16 + l4 * 4 + r;
        tl[trow * 136 + col] = f2bf(acc[m][n][r] + bv[n]);
      }
    }
  __syncthreads();

  // ---- copy out: [t][b][col'], 16B stores
  const int b = m0 >> 10;
  const int bgrp = b >> 2, b_loc = b & 3;
  const int t0 = m0 & 1023;
#pragma unroll
  for (int it = 0; it < 8; ++it) {
    int idx = it * 256 + tid;
    int row = idx >> 4, ch = idx & 15;
    uint4 v = *(const uint4*)(tl + row * 136 + ch * 8);
    u64 off = ((u64)((dir * 16 + bgrp) * 1024 + (t0 + row))) * 4096ull
              + (u64)(b_loc * 1024 + n0 + ch * 8);
    *(uint4*)(xw2 + off) = v;
  }
}

// ================= recurrence: 32 independent blocks (champion, round 8) ====
// bid: dir = bid>>4, bgrp = bid&15 (4 batches). 1024 threads = 16 waves.
// A rows replicated {b0 b0 b0 b0 b1 ...} -> C row = batch l4, acc[0] per lane.
// U kt0..5 in regs (96/lane — the proven-safe register point; 128 triggers
// allocator demotion, rounds 10/12), kt6..7 in LDS (128KB). xw 3-deep LDS
// prefetch via global_load_lds; vmcnt(1) barrier keeps newest prefetch in flight.
__global__ __launch_bounds__(1024) void k_rec(
    const ushort* __restrict__ xw2, const ushort* __restrict__ ut,
    const float* __restrict__ pif, const float* __restrict__ pff, const float* __restrict__ pof,
    const float* __restrict__ pib, const float* __restrict__ pfb, const float* __restrict__ pob,
    float* __restrict__ out)
{
  const int bid = blockIdx.x;
  const int dir = bid >> 4;
  const int bgrp = bid & 15;
  const int tid = threadIdx.x;
  const int lane = tid & 63, wv = tid >> 6;
  const int l15 = lane & 15, l4 = lane >> 4;
  const int u = wv * 16 + l15;       // unit 0..255

  // LDS: uld 128KB + hst 4.25KB + xsl 24KB = 160,000 B
  __shared__ __align__(16) ushort uld[65536];   // [wv][kt-6][g][lane*8]
  __shared__ __align__(16) ushort hst[2176];    // [2 slot][4 b][272]
  __shared__ __align__(16) ushort xsl[12288];   // [3 slot][4 b][1024 col']

  const float* piP = dir ? pib : pif;
  const float* pfP = dir ? pfb : pff;
  const float* poP = dir ? pob : pof;
  const float ppi = piP[u], ppf = pfP[u], ppo = poP[u];

  // U fragments (permuted cols: row of ut = u*4+g)
  const ushort* U = ut + dir * 262144;
  bf16x8 ufr[6][4];
#pragma unroll
  for (int g = 0; g < 4; ++g) {
    const ushort* up = U + (u * 4 + g) * 256;
#pragma unroll
    for (int kt = 0; kt < 6; ++kt)
      ufr[kt][g] = *(const bf16x8*)(up + kt * 32 + l4 * 8);
#pragma unroll
    for (int kt = 6; kt < 8; ++kt)
      *(bf16x8*)(uld + wv * 4096 + ((kt - 6) * 4 + g) * 512 + lane * 8) =
          *(const bf16x8*)(up + kt * 32 + l4 * 8);
  }
  for (int i = tid; i < 2176; i += 1024) hst[i] = 0;

  const ushort* xwbase = xw2 + (u64)(dir * 16 + bgrp) * 1024ull * 4096ull;

  // prologue: stage t=0 -> slot0, t=1 -> slot1
  if (tid < 512) {
    const ushort* s0 = xwbase + (u64)(dir ? 1023 : 0) * 4096ull + (uint)tid * 8u;
    const ushort* s1 = xwbase + (u64)(dir ? 1022 : 1) * 4096ull + (uint)tid * 8u;
    gload_lds16(s0, &xsl[(tid >> 6) * 512]);
    gload_lds16(s1, &xsl[4096 + (tid >> 6) * 512]);
  }
  __syncthreads();

  float cr = 0.f;
  float* outp = out + ((u64)(bgrp * 4 + l4) * 1024ull) * 512ull + (u64)(dir * 256 + u);
  int scur = 0;

  for (int t = 0; t < 1024; ++t) {
    // ---- MFMA: A from hst slot (t+1)&1, row = l15>>2 (batch), k = units
    const ushort* sA = hst + ((t + 1) & 1) * 1088 + (l15 >> 2) * 272 + l4 * 8;
    f32x4 acc0 = {0.f, 0.f, 0.f, 0.f}, acc1 = acc0, acc2 = acc0, acc3 = acc0;
#pragma unroll
    for (int kt = 0; kt < 6; ++kt) {
      bf16x8 a = *(const bf16x8*)(sA + kt * 32);
      acc0 = __builtin_amdgcn_mfma_f32_16x16x32_bf16(a, ufr[kt][0], acc0, 0, 0, 0);
      acc1 = __builtin_amdgcn_mfma_f32_16x16x32_bf16(a, ufr[kt][1], acc1, 0, 0, 0);
      acc2 = __builtin_amdgcn_mfma_f32_16x16x32_bf16(a, ufr[kt][2], acc2, 0, 0, 0);
      acc3 = __builtin_amdgcn_mfma_f32_16x16x32_bf16(a, ufr[kt][3], acc3, 0, 0, 0);
    }
#pragma unroll
    for (int kt = 6; kt < 8; ++kt) {
      bf16x8 a = *(const bf16x8*)(sA + kt * 32);
      const ushort* ub = uld + wv * 4096 + (kt - 6) * 2048 + lane * 8;
      acc0 = __builtin_amdgcn_mfma_f32_16x16x32_bf16(a, *(const bf16x8*)(ub), acc0, 0, 0, 0);
      acc1 = __builtin_amdgcn_mfma_f32_16x16x32_bf16(a, *(const bf16x8*)(ub + 512), acc1, 0, 0, 0);
      acc2 = __builtin_amdgcn_mfma_f32_16x16x32_bf16(a, *(const bf16x8*)(ub + 1024), acc2, 0, 0, 0);
      acc3 = __builtin_amdgcn_mfma_f32_16x16x32_bf16(a, *(const bf16x8*)(ub + 1536), acc3, 0, 0, 0);
    }

    // ---- elementwise: every lane owns (batch=l4, unit=u) via acc[0]
    u64 xv = *(const u64*)(xsl + scur * 4096 + (l4 << 10) + (u << 2));
    {
      float cc = cr;
      float gi = acc0[0] + bf2f((ushort)xv);
      float gf = acc1[0] + bf2f((ushort)(xv >> 16));
      float gg = acc2[0] + bf2f((ushort)(xv >> 32));
      float go = acc3[0] + bf2f((ushort)(xv >> 48));
      float iv = fsig(gi + ppi * cc);
      float fv = fsig(gf + ppf * cc);
      float cn = fv * cc + iv * ftanh(gg);
      float ov = fsig(go + ppo * cn);
      float h = ov * ftanh(cn);
      cr = cn;
      hst[(t & 1) * 1088 + l4 * 272 + u] = f2bf(h);
      const int tout = dir ? (1023 - t) : t;
      outp[(u64)tout * 512ull] = h;
    }

    // ---- stage t+2 into slot (scur+2)%3
    if (t + 2 < 1024 && tid < 512) {
      const int snxt = (scur >= 1) ? (scur - 1) : 2;
      const ushort* src = xwbase + (u64)(dir ? 1021 - t : t + 2) * 4096ull + (uint)tid * 8u;
      gload_lds16(src, &xsl[snxt * 4096 + (tid >> 6) * 512]);
    }

    // ---- per-step sync: keep newest prefetch in flight (vmcnt(1))
    asm volatile("s_waitcnt vmcnt(1) lgkmcnt(0)\n\ts_barrier" ::: "memory");
    scur = (scur == 2) ? 0 : (scur + 1);
  }
}

// ================= dropout (exact JAX threefry, in-place on out) =================
#define TFR(r) { x0 += x1; x1 = (x1 << (r)) | (x1 >> (32 - (r))); x1 ^= x0; }
#define RND4A TFR(13) TFR(15) TFR(26) TFR(6)
#define RND4B TFR(17) TFR(29) TFR(16) TFR(24)

static __device__ __forceinline__ void threefry(uint c0, uint c1, uint& y0, uint& y1) {
  const uint k0 = 0u, k1 = 42u;
  const uint ks2 = k0 ^ k1 ^ 0x1BD11BDAu;
  uint x0 = c0 + k0, x1 = c1 + k1;
  RND4A x0 += k1;  x1 += ks2 + 1u;
  RND4B x0 += ks2; x1 += k0 + 2u;
  RND4A x0 += k0;  x1 += k1 + 3u;
  RND4B x0 += k1;  x1 += ks2 + 4u;
  RND4A x0 += ks2; x1 += k0 + 5u;
  y0 = x0; y1 = x1;
}

__global__ __launch_bounds__(256) void k_drop(float* out, uint n) {
  uint i = blockIdx.x * 256u + threadIdx.x;
  if (i < n) {
    uint y0, y1;
    threefry(0u, i, y0, y1);
    uint w = y0 ^ y1;
    float v = out[i];
    out[i] = (w >> 31) ? 0.0f : v * 2.0f;
  }
}

// ================= host =================
extern "C" void kernel_launch(void* const* d_in, const int* in_sizes, int n_in,
                              void* d_out, int out_size, void* d_ws, size_t ws_size,
                              hipStream_t stream)
{
  const float* x   = (const float*)d_in[0];
  const float* Wf  = (const float*)d_in[1];
  const float* Uf  = (const float*)d_in[2];
  const float* bf_ = (const float*)d_in[3];
  const float* pif = (const float*)d_in[4];
  const float* pff = (const float*)d_in[5];
  const float* pof = (const float*)d_in[6];
  const float* Wb  = (const float*)d_in[7];
  const float* Ub  = (const float*)d_in[8];
  const float* bb_ = (const float*)d_in[9];
  const float* pib = (const float*)d_in[10];
  const float* pfb = (const float*)d_in[11];
  const float* pob = (const float*)d_in[12];
  float* out = (float*)d_out;
  char* ws = (char*)d_ws;

  if (ws_size < WS_NEED) {
    hipMemsetAsync(d_out, 0, (size_t)out_size * 4, stream);
    return;
  }

  ushort* xwp = (ushort*)(ws + XW_OFF);
  ushort* xbp = (ushort*)(ws + XB_OFF);
  ushort* wtp = (ushort*)(ws + WT_OFF);
  ushort* utp = (ushort*)(ws + UT_OFF);

  k_convert<<<12288, 256, 0, stream>>>(x, Wf, Wb, Uf, Ub, xbp, wtp, utp);
  k_gemm<<<dim3(512, 8, 2), 256, 0, stream>>>(xbp, wtp, bf_, bb_, xwp);
  k_rec<<<32, 1024, 0, stream>>>(xwp, utp, pif, pff, pof, pib, pfb, pob, out);
  k_drop<<<(out_size + 255) / 256, 256, 0, stream>>>(out, (uint)out_size);
}